// Round 1
// baseline (1167.563 us; speedup 1.0000x reference)
//
#include <hip/hip_runtime.h>
#include <math.h>

#define B_ 16
#define T_ 4
#define D_ 1024
#define H_ 16
#define DH_ 64
#define S_ 8192
#define NW 8                       // waves per block in attention kernel
#define ROWS_PER_WAVE (S_ / NW)    // 1024
#define UNROLL 4

// ---------------------------------------------------------------------------
// Online-softmax step for 4 query rows. Lane layout: lane = s_sub*16 + d4.
// kf/vf hold this lane's float4 slice (dims d4*4..d4*4+3) of K/V row s_sub.
// After the 16-lane butterfly, every lane holds the full dot for its s_sub.
// Each (wave, s_sub) pair is an independent online-softmax stream.
// ---------------------------------------------------------------------------
__device__ __forceinline__ void online_step(const float4* q4, const float4& kf,
                                            const float4& vf, float* m, float* l,
                                            float4* o) {
  float sc[T_];
#pragma unroll
  for (int t = 0; t < T_; ++t)
    sc[t] = q4[t].x * kf.x + q4[t].y * kf.y + q4[t].z * kf.z + q4[t].w * kf.w;
#pragma unroll
  for (int mask = 1; mask < 16; mask <<= 1) {
#pragma unroll
    for (int t = 0; t < T_; ++t) sc[t] += __shfl_xor(sc[t], mask);
  }
#pragma unroll
  for (int t = 0; t < T_; ++t) {
    float s = sc[t] * 0.125f;  // 1/sqrt(64)
    float nm = fmaxf(m[t], s);
    float al = __expf(m[t] - nm);
    float p = __expf(s - nm);
    m[t] = nm;
    l[t] = fmaf(l[t], al, p);
    o[t].x = fmaf(o[t].x, al, p * vf.x);
    o[t].y = fmaf(o[t].y, al, p * vf.y);
    o[t].z = fmaf(o[t].z, al, p * vf.z);
    o[t].w = fmaf(o[t].w, al, p * vf.w);
  }
}

// Merge two online-softmax streams held by lanes differing in bit `mask`.
__device__ __forceinline__ void merge_xor(int mask, float* m, float* l, float4* o) {
#pragma unroll
  for (int t = 0; t < T_; ++t) {
    float om = __shfl_xor(m[t], mask);
    float ol = __shfl_xor(l[t], mask);
    float4 oo;
    oo.x = __shfl_xor(o[t].x, mask);
    oo.y = __shfl_xor(o[t].y, mask);
    oo.z = __shfl_xor(o[t].z, mask);
    oo.w = __shfl_xor(o[t].w, mask);
    float nm = fmaxf(m[t], om);
    float ea = __expf(m[t] - nm);
    float eb = __expf(om - nm);
    m[t] = nm;
    l[t] = l[t] * ea + ol * eb;
    o[t].x = o[t].x * ea + oo.x * eb;
    o[t].y = o[t].y * ea + oo.y * eb;
    o[t].z = o[t].z * ea + oo.z * eb;
    o[t].w = o[t].w * ea + oo.w * eb;
  }
}

// ---------------------------------------------------------------------------
// Attention: one block per (b,h); 8 waves stream disjoint s-ranges of the KV
// cache with online softmax, then merge (shfl within wave, LDS across waves).
// qkv: [B*T, 3*D] rows (q | k | v each D wide). attn_out: [B*T, D] fp32.
// ---------------------------------------------------------------------------
__global__ __launch_bounds__(NW * 64) void attn_kernel(
    const float* __restrict__ qkv, const float* __restrict__ cache_k,
    const float* __restrict__ cache_v, float* __restrict__ attn_out) {
  const int bh = blockIdx.x;
  const int b = bh >> 4;
  const int h = bh & 15;
  const int tid = threadIdx.x;
  const int wave = tid >> 6;
  const int lane = tid & 63;
  const int s_sub = lane >> 4;  // 0..3: which of 4 rows this lane helps with
  const int d4 = lane & 15;     // 0..15: which float4 of the 64-dim head

  // Per-lane q fragments (dims d4*4 .. d4*4+3) for the 4 query rows.
  float4 q4[T_];
#pragma unroll
  for (int t = 0; t < T_; ++t)
    q4[t] = *(const float4*)(qkv + (size_t)((b * T_ + t) * 3 * D_ + h * DH_ + d4 * 4));

  // cache_k[b, s, h, dh]: stride over s is H*DH = D_ floats.
  const float* kbase = cache_k + (size_t)b * S_ * D_ + h * DH_ + d4 * 4;
  const float* vbase = cache_v + (size_t)b * S_ * D_ + h * DH_ + d4 * 4;

  float m[T_], l[T_];
  float4 o[T_];
#pragma unroll
  for (int t = 0; t < T_; ++t) {
    m[t] = -1e30f;
    l[t] = 0.f;
    o[t] = make_float4(0.f, 0.f, 0.f, 0.f);
  }

  const int row0 = wave * ROWS_PER_WAVE + s_sub;
  for (int it = 0; it < ROWS_PER_WAVE / (4 * UNROLL); ++it) {
    const float* kp = kbase + (size_t)(row0 + it * 4 * UNROLL) * D_;
    const float* vp = vbase + (size_t)(row0 + it * 4 * UNROLL) * D_;
    float4 kf[UNROLL], vf[UNROLL];
#pragma unroll
    for (int u = 0; u < UNROLL; ++u) {  // issue all loads up front (MLP)
      kf[u] = *(const float4*)(kp + (size_t)u * 4 * D_);
      vf[u] = *(const float4*)(vp + (size_t)u * 4 * D_);
    }
#pragma unroll
    for (int u = 0; u < UNROLL; ++u) online_step(q4, kf[u], vf[u], m, l, o);
  }

  // The T_=4 freshly-projected K/V rows (s = S..S+3): one extra group on
  // wave 0, row s_sub == new token index t.
  if (wave == 0) {
    const float* krow = qkv + (size_t)((b * T_ + s_sub) * 3 * D_ + D_ + h * DH_ + d4 * 4);
    const float* vrow = qkv + (size_t)((b * T_ + s_sub) * 3 * D_ + 2 * D_ + h * DH_ + d4 * 4);
    float4 kf = *(const float4*)krow;
    float4 vf = *(const float4*)vrow;
    online_step(q4, kf, vf, m, l, o);
  }

  // Merge the 4 s_sub streams within the wave (bits 4 and 5 of the lane id).
  merge_xor(16, m, l, o);
  merge_xor(32, m, l, o);

  // Cross-wave merge via LDS.
  __shared__ float lm[NW][T_];
  __shared__ float ll[NW][T_];
  __shared__ float lo[NW][T_][DH_];
  if (lane < 16) {  // s_sub == 0 group; d4 == lane
#pragma unroll
    for (int t = 0; t < T_; ++t) {
      if (lane == 0) {
        lm[wave][t] = m[t];
        ll[wave][t] = l[t];
      }
      *(float4*)(&lo[wave][t][lane * 4]) = o[t];
    }
  }
  __syncthreads();
  if (tid < DH_) {
    const int d = tid;
#pragma unroll
    for (int t = 0; t < T_; ++t) {
      float M = -1e30f;
#pragma unroll
      for (int w = 0; w < NW; ++w) M = fmaxf(M, lm[w][t]);
      float L = 0.f, O = 0.f;
#pragma unroll
      for (int w = 0; w < NW; ++w) {
        float e = __expf(lm[w][t] - M);
        L += ll[w][t] * e;
        O += lo[w][t][d] * e;
      }
      attn_out[(size_t)(b * T_ + t) * D_ + h * DH_ + d] = O / L;
    }
  }
}

// ---------------------------------------------------------------------------
// C[M=64, N] = A[64, K=1024] * W[N, K]^T.  64x64 tile per block, 4x4 per
// thread, K staged in 32-wide LDS chunks. grid.x = N/64.
// ---------------------------------------------------------------------------
__global__ __launch_bounds__(256) void gemm_xwt(const float* __restrict__ A,
                                                const float* __restrict__ W,
                                                float* __restrict__ C, int N) {
  const int K = 1024;
  __shared__ float As[32][65];
  __shared__ float Bs[32][65];
  const int tid = threadIdx.x;
  const int n0 = blockIdx.x * 64;
  const int tx = tid & 15;
  const int ty = tid >> 4;
  const int lrow = tid >> 2;       // 0..63
  const int lk = (tid & 3) * 8;    // 0,8,16,24

  float acc[4][4] = {};
  for (int k0 = 0; k0 < K; k0 += 32) {
    float4 a0 = *(const float4*)(A + (size_t)lrow * K + k0 + lk);
    float4 a1 = *(const float4*)(A + (size_t)lrow * K + k0 + lk + 4);
    float4 b0 = *(const float4*)(W + (size_t)(n0 + lrow) * K + k0 + lk);
    float4 b1 = *(const float4*)(W + (size_t)(n0 + lrow) * K + k0 + lk + 4);
    As[lk + 0][lrow] = a0.x; As[lk + 1][lrow] = a0.y;
    As[lk + 2][lrow] = a0.z; As[lk + 3][lrow] = a0.w;
    As[lk + 4][lrow] = a1.x; As[lk + 5][lrow] = a1.y;
    As[lk + 6][lrow] = a1.z; As[lk + 7][lrow] = a1.w;
    Bs[lk + 0][lrow] = b0.x; Bs[lk + 1][lrow] = b0.y;
    Bs[lk + 2][lrow] = b0.z; Bs[lk + 3][lrow] = b0.w;
    Bs[lk + 4][lrow] = b1.x; Bs[lk + 5][lrow] = b1.y;
    Bs[lk + 6][lrow] = b1.z; Bs[lk + 7][lrow] = b1.w;
    __syncthreads();
#pragma unroll
    for (int kk = 0; kk < 32; ++kk) {
      float a[4], bb[4];
#pragma unroll
      for (int i = 0; i < 4; ++i) a[i] = As[kk][ty * 4 + i];
#pragma unroll
      for (int j = 0; j < 4; ++j) bb[j] = Bs[kk][tx * 4 + j];
#pragma unroll
      for (int i = 0; i < 4; ++i)
#pragma unroll
        for (int j = 0; j < 4; ++j) acc[i][j] = fmaf(a[i], bb[j], acc[i][j]);
    }
    __syncthreads();
  }
#pragma unroll
  for (int i = 0; i < 4; ++i)
#pragma unroll
    for (int j = 0; j < 4; ++j)
      C[(size_t)(ty * 4 + i) * N + n0 + tx * 4 + j] = acc[i][j];
}

extern "C" void kernel_launch(void* const* d_in, const int* in_sizes, int n_in,
                              void* d_out, int out_size, void* d_ws, size_t ws_size,
                              hipStream_t stream) {
  const float* x = (const float*)d_in[0];        // [B,T,D]
  const float* cache_k = (const float*)d_in[1];  // [B,S,H,DH]
  const float* cache_v = (const float*)d_in[2];  // [B,S,H,DH]
  const float* w_qkv = (const float*)d_in[3];    // [3D, D]
  const float* w_proj = (const float*)d_in[4];   // [D, D]
  float* out = (float*)d_out;                    // [B,T,D]

  float* qkv = (float*)d_ws;                   // 64 * 3072 floats
  float* attn = qkv + (size_t)B_ * T_ * 3 * D_;  // 64 * 1024 floats

  // 1) qkv = x @ w_qkv^T   (M=64, N=3072, K=1024)
  gemm_xwt<<<3 * D_ / 64, 256, 0, stream>>>(x, w_qkv, qkv, 3 * D_);
  // 2) streaming attention over the KV cache + 4 new rows
  attn_kernel<<<B_ * H_, NW * 64, 0, stream>>>(qkv, cache_k, cache_v, attn);
  // 3) out = attn @ w_proj^T   (M=64, N=1024, K=1024)
  gemm_xwt<<<D_ / 64, 256, 0, stream>>>(attn, w_proj, out, D_);
}